// Round 2
// baseline (1681.751 us; speedup 1.0000x reference)
//
#include <hip/hip_runtime.h>
#include <hip/hip_bf16.h>
#include <math.h>
#include <stdint.h>

#define NN 10000
#define EE 100000
#define DD 768
#define HH 4
#define CC 192
#define EDIM 16
#define NREL 10
#define MP 10048           // NN padded to multiple of 64 for GEMM tiles
#define SCALE 0.07216878364870322f   // 1/sqrt(192)

using short8  = __attribute__((ext_vector_type(8))) short;
using floatx4 = __attribute__((ext_vector_type(4))) float;

// ---------------- helpers ----------------

__device__ __forceinline__ float waveRedSum(float v) {
#pragma unroll
    for (int m = 32; m > 0; m >>= 1) v += __shfl_xor(v, m);
    return v;
}

__device__ __forceinline__ __hip_bfloat16 rd_any(const void* p, long long j, int bf) {
    if (bf) return ((const __hip_bfloat16*)p)[j];
    return __float2bfloat16(((const float*)p)[j]);
}

// ---------------- dtype detection ----------------
// f32-packed edge_attr: relation ids are exact small ints -> low 16 bits of the
// f32 are ALWAYS zero at ushort index 4t. bf16-packed: ushort 4t is rel_{2t}'s
// bf16 bits, nonzero ~90% of the time. 64 samples separate these perfectly.
__global__ void detect_kernel(const void* edge_attr, int* flag) {
    const unsigned short* p = (const unsigned short*)edge_attr;
    int t = threadIdx.x;
    int nz = (p[4 * t] != 0) ? 1 : 0;
    unsigned long long m = __ballot(nz);
    if (t == 0) *flag = (__popcll(m) > 8) ? 1 : 0;
}

// ---------------- input conversion ----------------

__global__ __launch_bounds__(256) void cvt_big(
    const void* x, const void* Wk, const void* Wq, const void* Wv,
    const void* Ws, const void* We, const int* flag,
    __hip_bfloat16* hb, __hip_bfloat16* Wkb, __hip_bfloat16* Wqb,
    __hip_bfloat16* Wvb, __hip_bfloat16* Wsb, __hip_bfloat16* Web) {
    long long i = (long long)blockIdx.x * 256 + threadIdx.x;
    int bf = *flag;
    const long long NX = (long long)NN * DD;       // 7,680,000
    const long long NW = 3LL * DD * DD;            // 1,769,472
    const long long NE2 = 3LL * EDIM * DD;         // 36,864
    if (i < NX) { hb[i] = rd_any(x, i, bf); return; } i -= NX;
    if (i < NW) { Wkb[i] = rd_any(Wk, i, bf); return; } i -= NW;
    if (i < NW) { Wqb[i] = rd_any(Wq, i, bf); return; } i -= NW;
    if (i < NW) { Wvb[i] = rd_any(Wv, i, bf); return; } i -= NW;
    if (i < NW) { Wsb[i] = rd_any(Ws, i, bf); return; } i -= NW;
    if (i < NE2) { Web[i] = rd_any(We, i, bf); return; } i -= NE2;
    if (i < (long long)(MP - NN) * DD) hb[(long long)NN * DD + i] = __float2bfloat16(0.0f);
}

__global__ __launch_bounds__(256) void cvt_small(
    const void* ea, const void* rel, const void* Wed, const void* bed,
    const void* bk, const void* bq, const void* bv, const void* bs,
    const void* lg, const void* lb, const int* flag,
    __hip_bfloat16* eab, __hip_bfloat16* relb, __hip_bfloat16* Wedb,
    __hip_bfloat16* bedb, __hip_bfloat16* bkb, __hip_bfloat16* bqb,
    __hip_bfloat16* bvb, __hip_bfloat16* bsb, __hip_bfloat16* lgb,
    __hip_bfloat16* lbb) {
    long long i = (long long)blockIdx.x * 256 + threadIdx.x;
    int bf = *flag;
    if (i < 2LL * EE) { eab[i] = rd_any(ea, i, bf); return; } i -= 2LL * EE;
    if (i < NREL * (EDIM - 1)) { relb[i] = rd_any(rel, i, bf); return; } i -= NREL * (EDIM - 1);
    if (i < EDIM * EDIM) { Wedb[i] = rd_any(Wed, i, bf); return; } i -= EDIM * EDIM;
    if (i < EDIM) { bedb[i] = rd_any(bed, i, bf); return; } i -= EDIM;
    if (i < 3 * DD) { bkb[i] = rd_any(bk, i, bf); return; } i -= 3 * DD;
    if (i < 3 * DD) { bqb[i] = rd_any(bq, i, bf); return; } i -= 3 * DD;
    if (i < 3 * DD) { bvb[i] = rd_any(bv, i, bf); return; } i -= 3 * DD;
    if (i < 3 * DD) { bsb[i] = rd_any(bs, i, bf); return; } i -= 3 * DD;
    if (i < DD) { lgb[i] = rd_any(lg, i, bf); return; } i -= DD;
    if (i < DD) { lbb[i] = rd_any(lb, i, bf); return; }
}

// ---------------- CSR build (incoming edges per dst) ----------------

__global__ __launch_bounds__(256) void zero_counts(int* counts) {
    int i = blockIdx.x * 256 + threadIdx.x;
    if (i < NN) counts[i] = 0;
}

__global__ __launch_bounds__(256) void count_kernel(const int* ei, int* counts) {
    int e = blockIdx.x * 256 + threadIdx.x;
    if (e < EE) atomicAdd(&counts[ei[EE + e]], 1);
}

__global__ __launch_bounds__(256) void scan_kernel(const int* counts, int* rowptr) {
    __shared__ int sdata[256];
    __shared__ int srun;
    int t = threadIdx.x;
    if (t == 0) { srun = 0; rowptr[0] = 0; }
    __syncthreads();
    for (int base = 0; base < NN; base += 256) {
        int v = (base + t < NN) ? counts[base + t] : 0;
        sdata[t] = v;
        __syncthreads();
        for (int off = 1; off < 256; off <<= 1) {
            int add = (t >= off) ? sdata[t - off] : 0;
            __syncthreads();
            sdata[t] += add;
            __syncthreads();
        }
        if (base + t < NN) rowptr[base + t + 1] = srun + sdata[t];
        __syncthreads();
        if (t == 255) srun += sdata[255];
        __syncthreads();
    }
}

__global__ __launch_bounds__(256) void cursor_kernel(const int* rowptr, int* cursor) {
    int i = blockIdx.x * 256 + threadIdx.x;
    if (i < NN) cursor[i] = rowptr[i];
}

__global__ __launch_bounds__(256) void fill_kernel(const int* ei, int* cursor, int* eids) {
    int e = blockIdx.x * 256 + threadIdx.x;
    if (e < EE) {
        int d = ei[EE + e];
        int pos = atomicAdd(&cursor[d], 1);
        eids[pos] = e;
    }
}

// ---------------- edge features ----------------

__global__ __launch_bounds__(256) void ef_kernel(
    const __hip_bfloat16* __restrict__ eab, const __hip_bfloat16* __restrict__ relb,
    const __hip_bfloat16* __restrict__ Wedb, const __hip_bfloat16* __restrict__ bedb,
    float* __restrict__ ef) {
    int idx = blockIdx.x * 256 + threadIdx.x;
    if (idx >= EE * EDIM) return;
    int e = idx >> 4, j = idx & 15;
    int rid = (int)((float)eab[e * 2 + 0]);
    rid = min(max(rid, 0), NREL - 1);
    float w = (float)eab[e * 2 + 1];
    float s = (float)bedb[j];
#pragma unroll
    for (int i = 0; i < 15; i++)
        s += (float)relb[rid * 15 + i] * (float)Wedb[i * EDIM + j];
    s += w * (float)Wedb[15 * EDIM + j];
    ef[idx] = s;
}

// ---------------- GEMM: C(bf16)[M,Nc] = A(bf16)[MP,K] @ B(bf16)[K,Nc] + bias ----------------

__global__ __launch_bounds__(256) void gemm_bf16(
    const __hip_bfloat16* __restrict__ A, const __hip_bfloat16* __restrict__ B,
    const __hip_bfloat16* __restrict__ bias, __hip_bfloat16* __restrict__ C,
    int M, int K, int Nc) {
    __shared__ unsigned short As[64][40];  // [m][k]
    __shared__ unsigned short Bs[64][40];  // [n][k] (transposed)
    const int tid  = threadIdx.x;
    const int wid  = tid >> 6, lane = tid & 63;
    const int quad = lane >> 4, l15 = lane & 15;
    const int m0 = blockIdx.y * 64, n0 = blockIdx.x * 64;
    const int arow = tid >> 2, acol = (tid & 3) * 8;
    const int bkr = tid >> 3, bns = (tid & 7) * 8;
    floatx4 acc[4] = {};
    for (int k0 = 0; k0 < K; k0 += 32) {
        *(float4*)(&As[arow][acol]) =
            *(const float4*)(A + (size_t)(m0 + arow) * K + k0 + acol);
        float4 bv4 = *(const float4*)(B + (size_t)(k0 + bkr) * Nc + n0 + bns);
        const unsigned short* bp = (const unsigned short*)&bv4;
#pragma unroll
        for (int i = 0; i < 8; i++) Bs[bns + i][bkr] = bp[i];
        __syncthreads();
        short8 a = *(const short8*)(&As[wid * 16 + l15][quad * 8]);
#pragma unroll
        for (int t = 0; t < 4; t++) {
            short8 b = *(const short8*)(&Bs[t * 16 + l15][quad * 8]);
            acc[t] = __builtin_amdgcn_mfma_f32_16x16x32_bf16(a, b, acc[t], 0, 0, 0);
        }
        __syncthreads();
    }
#pragma unroll
    for (int t = 0; t < 4; t++) {
        int col = n0 + t * 16 + l15;
        float bval = (float)bias[col];
#pragma unroll
        for (int r = 0; r < 4; r++) {
            int row = m0 + wid * 16 + quad * 4 + r;
            if (row < M) C[(size_t)row * Nc + col] = __float2bfloat16(acc[t][r] + bval);
        }
    }
}

// ---------------- attention ----------------

// Qe[n,h,j] = dot(q[n, h*C:(h+1)*C], We_l[j, h*C:(h+1)*C])
__global__ __launch_bounds__(256) void qe_kernel(
    const __hip_bfloat16* __restrict__ qb, const __hip_bfloat16* __restrict__ Wel,
    float* __restrict__ Qe) {
    int idx = blockIdx.x * 256 + threadIdx.x;
    if (idx >= NN * HH * EDIM) return;
    int n = idx >> 6, hj = idx & 63, hh = hj >> 4, j = hj & 15;
    const __hip_bfloat16* qrow = qb + (size_t)n * DD + hh * CC;
    const __hip_bfloat16* wrow = Wel + (size_t)j * DD + hh * CC;
    float s = 0.f;
    for (int c = 0; c < CC; c++) s += (float)qrow[c] * (float)wrow[c];
    Qe[idx] = s;
}

// one wave per edge: alpha[e,h] = scale*(dot(q[dst],k[src]) + dot(Qe[dst],ef[e]))
__global__ __launch_bounds__(256) void edge_alpha(
    const __hip_bfloat16* __restrict__ qb, const __hip_bfloat16* __restrict__ kb,
    const float* __restrict__ Qe, const float* __restrict__ ef,
    const int* __restrict__ ei, float* __restrict__ alpha) {
    int wv = blockIdx.x * 4 + (threadIdx.x >> 6);
    int lane = threadIdx.x & 63;
    int s = ei[wv], d = ei[EE + wv];
    const __hip_bfloat16* qrow = qb + (size_t)d * DD;
    const __hip_bfloat16* krow = kb + (size_t)s * DD;
    float p0 = 0.f, p1 = 0.f, p2 = 0.f, p3 = 0.f;
#pragma unroll
    for (int i = 0; i < 12; i++) {
        int ch = lane + (i << 6);
        float p = (float)qrow[ch] * (float)krow[ch];
        if (i < 3) p0 += p; else if (i < 6) p1 += p; else if (i < 9) p2 += p; else p3 += p;
    }
#pragma unroll
    for (int m = 1; m < 64; m <<= 1) {
        p0 += __shfl_xor(p0, m); p1 += __shfl_xor(p1, m);
        p2 += __shfl_xor(p2, m); p3 += __shfl_xor(p3, m);
    }
    if (lane < 4) {
        float qk = (lane == 0) ? p0 : (lane == 1) ? p1 : (lane == 2) ? p2 : p3;
        const float* Qrow = Qe + (size_t)d * 64 + lane * 16;
        const float* erow = ef + (size_t)wv * 16;
        float qe = 0.f;
#pragma unroll
        for (int j = 0; j < 16; j++) qe += Qrow[j] * erow[j];
        alpha[wv * 4 + lane] = (qk + qe) * SCALE;
    }
}

// per (node, head): softmax over incoming edges, normalized in place (no atomics)
__global__ __launch_bounds__(256) void node_soft(
    const int* __restrict__ rowptr, const int* __restrict__ eids,
    float* __restrict__ alpha) {
    int idx = blockIdx.x * 256 + threadIdx.x;
    if (idx >= NN * HH) return;
    int n = idx >> 2, hh = idx & 3;
    int s0 = rowptr[n], s1 = rowptr[n + 1];
    float m = -1e30f;
    for (int p = s0; p < s1; p++) m = fmaxf(m, alpha[eids[p] * 4 + hh]);
    float den = 0.f;
    for (int p = s0; p < s1; p++) den += expf(alpha[eids[p] * 4 + hh] - m);
    float inv = 1.0f / (den + 1e-16f);
    for (int p = s0; p < s1; p++) {
        int a = eids[p] * 4 + hh;
        alpha[a] = expf(alpha[a] - m) * inv;
    }
}

// one wave per node: h[n] = sum_e a*(v[src]) + (sum_e a*ef[e]) @ We + skip[n] [, gelu]
__global__ __launch_bounds__(256) void node_gather(
    const int* __restrict__ rowptr, const int* __restrict__ eids,
    const int* __restrict__ ei, const __hip_bfloat16* __restrict__ vb,
    const __hip_bfloat16* __restrict__ skipb, const float* __restrict__ anorm,
    const float* __restrict__ ef, const __hip_bfloat16* __restrict__ Wel,
    __hip_bfloat16* __restrict__ hb, int do_gelu) {
    __shared__ float S_l[4][64];
    int wid = threadIdx.x >> 6, lane = threadIdx.x & 63;
    int n = blockIdx.x * 4 + wid;   // grid = 2500 blocks, exact
    int s0 = rowptr[n], s1 = rowptr[n + 1];
    float acc[12];
#pragma unroll
    for (int i = 0; i < 12; i++) acc[i] = 0.f;
    int sh = lane >> 4, sj = lane & 15;
    float sacc = 0.f;
    for (int p = s0; p < s1; p++) {
        int e = eids[p];
        int src = ei[e];
        float a0 = anorm[e * 4 + 0], a1 = anorm[e * 4 + 1];
        float a2 = anorm[e * 4 + 2], a3 = anorm[e * 4 + 3];
        const __hip_bfloat16* vrow = vb + (size_t)src * DD;
#pragma unroll
        for (int i = 0; i < 12; i++) {
            int ch = lane + (i << 6);
            float ah = (i < 3) ? a0 : (i < 6) ? a1 : (i < 9) ? a2 : a3;
            acc[i] += ah * (float)vrow[ch];
        }
        float ahS = (sh == 0) ? a0 : (sh == 1) ? a1 : (sh == 2) ? a2 : a3;
        sacc += ahS * ef[(size_t)e * 16 + sj];
    }
    S_l[wid][lane] = sacc;
    __syncthreads();
    const __hip_bfloat16* skrow = skipb + (size_t)n * DD;
    __hip_bfloat16* hrow = hb + (size_t)n * DD;
#pragma unroll
    for (int i = 0; i < 12; i++) {
        int ch = lane + (i << 6);
        int hh = ch / CC;
        float sv = 0.f;
#pragma unroll
        for (int j = 0; j < 16; j++)
            sv += S_l[wid][hh * 16 + j] * (float)Wel[(size_t)j * DD + ch];
        float val = acc[i] + sv + (float)skrow[ch];
        if (do_gelu) val = 0.5f * val * (1.0f + erff(val * 0.70710678118654752f));
        hrow[ch] = __float2bfloat16(val);
    }
}

// ---------------- LN + mean pool ----------------

__global__ __launch_bounds__(256) void ln_pool(
    const __hip_bfloat16* __restrict__ hb, const __hip_bfloat16* __restrict__ g,
    const __hip_bfloat16* __restrict__ b, float* __restrict__ partial) {
    int grp = blockIdx.x, t = threadIdx.x;
    int wid = t >> 6, lane = t & 63;
    __shared__ float red[4], red2[4];
    float g0 = (float)g[t], g1 = (float)g[t + 256], g2 = (float)g[t + 512];
    float b0 = (float)b[t], b1 = (float)b[t + 256], b2 = (float)b[t + 512];
    float a0 = 0.f, a1 = 0.f, a2 = 0.f;
    for (int r = 0; r < 250; r++) {
        const __hip_bfloat16* row = hb + (size_t)(grp * 250 + r) * DD;
        float x0 = (float)row[t], x1 = (float)row[t + 256], x2 = (float)row[t + 512];
        float s = waveRedSum(x0 + x1 + x2);
        float q = waveRedSum(x0 * x0 + x1 * x1 + x2 * x2);
        if (lane == 0) { red[wid] = s; red2[wid] = q; }
        __syncthreads();
        float mu = (red[0] + red[1] + red[2] + red[3]) * (1.0f / 768.0f);
        float ms = (red2[0] + red2[1] + red2[2] + red2[3]) * (1.0f / 768.0f);
        __syncthreads();
        float inv = 1.0f / sqrtf(ms - mu * mu + 1e-5f);
        a0 += (x0 - mu) * inv * g0 + b0;
        a1 += (x1 - mu) * inv * g1 + b1;
        a2 += (x2 - mu) * inv * g2 + b2;
    }
    partial[grp * DD + t]       = a0;
    partial[grp * DD + t + 256] = a1;
    partial[grp * DD + t + 512] = a2;
}

__global__ __launch_bounds__(256) void final_kernel(
    const float* __restrict__ partial, void* __restrict__ out,
    const int* __restrict__ flag) {
    int dd = blockIdx.x * 256 + threadIdx.x;
    if (dd >= DD) return;
    float s = 0.f;
    for (int g2 = 0; g2 < 40; g2++) s += partial[g2 * DD + dd];
    s *= (1.0f / 10000.0f);
    if (*flag) ((__hip_bfloat16*)out)[dd] = __float2bfloat16(s);
    else ((float*)out)[dd] = s;
}

// ---------------- launch ----------------

extern "C" void kernel_launch(void* const* d_in, const int* in_sizes, int n_in,
                              void* d_out, int out_size, void* d_ws, size_t ws_size,
                              hipStream_t stream) {
    const void* x         = d_in[0];
    const void* edge_attr = d_in[1];
    const int*  ei        = (const int*)d_in[2];
    const void* rel_emb   = d_in[3];
    const void* W_edge    = d_in[4];
    const void* b_edge    = d_in[5];
    const void* Wk        = d_in[6];
    const void* bk        = d_in[7];
    const void* Wq        = d_in[8];
    const void* bq        = d_in[9];
    const void* Wv        = d_in[10];
    const void* bv        = d_in[11];
    const void* We        = d_in[12];
    const void* Wskip     = d_in[13];
    const void* bskip     = d_in[14];
    const void* ln_g      = d_in[15];
    const void* ln_b      = d_in[16];

    char* ws = (char*)d_ws;
    // ---- workspace layout (~102.8 MB total) ----
    int*   flag    = (int*)(ws + 0);
    int*   counts  = (int*)(ws + 256);
    int*   rowptr  = (int*)(ws + 40448);
    int*   cursor  = (int*)(ws + 80640);
    int*   eids    = (int*)(ws + 120832);
    float* ef      = (float*)(ws + 520960);
    float* Qe      = (float*)(ws + 6921216);
    float* alpha   = (float*)(ws + 9481216);
    float* partial = (float*)(ws + 11081216);
    __hip_bfloat16* hb    = (__hip_bfloat16*)(ws + 11204096);   // MP*768
    __hip_bfloat16* qb    = (__hip_bfloat16*)(ws + 26637824);
    __hip_bfloat16* kb    = (__hip_bfloat16*)(ws + 41997824);
    __hip_bfloat16* vb    = (__hip_bfloat16*)(ws + 57357824);
    __hip_bfloat16* skipb = (__hip_bfloat16*)(ws + 72717824);
    __hip_bfloat16* Wkb   = (__hip_bfloat16*)(ws + 88077824);
    __hip_bfloat16* Wqb   = (__hip_bfloat16*)(ws + 91616768);
    __hip_bfloat16* Wvb   = (__hip_bfloat16*)(ws + 95155712);
    __hip_bfloat16* Wsb   = (__hip_bfloat16*)(ws + 98694656);
    __hip_bfloat16* Web   = (__hip_bfloat16*)(ws + 102233600);
    __hip_bfloat16* eab   = (__hip_bfloat16*)(ws + 102307328);
    __hip_bfloat16* relb  = (__hip_bfloat16*)(ws + 102707328);
    __hip_bfloat16* Wedb  = (__hip_bfloat16*)(ws + 102707840);
    __hip_bfloat16* bedb  = (__hip_bfloat16*)(ws + 102708352);
    __hip_bfloat16* bkb   = (__hip_bfloat16*)(ws + 102708608);
    __hip_bfloat16* bqb   = (__hip_bfloat16*)(ws + 102713216);
    __hip_bfloat16* bvb   = (__hip_bfloat16*)(ws + 102717824);
    __hip_bfloat16* bsb   = (__hip_bfloat16*)(ws + 102722432);
    __hip_bfloat16* lngb  = (__hip_bfloat16*)(ws + 102727040);
    __hip_bfloat16* lnbb  = (__hip_bfloat16*)(ws + 102728576);

    dim3 blk(256);

    detect_kernel<<<dim3(1), dim3(64), 0, stream>>>(edge_attr, flag);

    {
        long long tot = (long long)NN * DD + 4LL * 3 * DD * DD + 3LL * EDIM * DD
                        + (long long)(MP - NN) * DD;
        cvt_big<<<dim3((unsigned)((tot + 255) / 256)), blk, 0, stream>>>(
            x, Wk, Wq, Wv, Wskip, We, flag, hb, Wkb, Wqb, Wvb, Wsb, Web);
    }
    {
        long long tot = 2LL * EE + NREL * (EDIM - 1) + EDIM * EDIM + EDIM
                        + 4LL * 3 * DD + 2LL * DD;
        cvt_small<<<dim3((unsigned)((tot + 255) / 256)), blk, 0, stream>>>(
            edge_attr, rel_emb, W_edge, b_edge, bk, bq, bv, bskip, ln_g, ln_b,
            flag, eab, relb, Wedb, bedb, bkb, bqb, bvb, bsb, lngb, lnbb);
    }

    // CSR build
    zero_counts<<<dim3(40), blk, 0, stream>>>(counts);
    count_kernel<<<dim3((EE + 255) / 256), blk, 0, stream>>>(ei, counts);
    scan_kernel<<<dim3(1), blk, 0, stream>>>(counts, rowptr);
    cursor_kernel<<<dim3(40), blk, 0, stream>>>(rowptr, cursor);
    fill_kernel<<<dim3((EE + 255) / 256), blk, 0, stream>>>(ei, cursor, eids);

    ef_kernel<<<dim3((EE * EDIM) / 256), blk, 0, stream>>>(eab, relb, Wedb, bedb, ef);

    for (int l = 0; l < 3; l++) {
        const __hip_bfloat16* Wq_l = Wqb + (size_t)l * DD * DD;
        const __hip_bfloat16* Wk_l = Wkb + (size_t)l * DD * DD;
        const __hip_bfloat16* Wv_l = Wvb + (size_t)l * DD * DD;
        const __hip_bfloat16* Ws_l = Wsb + (size_t)l * DD * DD;
        const __hip_bfloat16* We_l = Web + (size_t)l * EDIM * DD;

        dim3 ggrid(DD / 64, MP / 64);  // 12 x 157
        gemm_bf16<<<ggrid, blk, 0, stream>>>(hb, Wq_l, bqb + l * DD, qb, NN, DD, DD);
        gemm_bf16<<<ggrid, blk, 0, stream>>>(hb, Wk_l, bkb + l * DD, kb, NN, DD, DD);
        gemm_bf16<<<ggrid, blk, 0, stream>>>(hb, Wv_l, bvb + l * DD, vb, NN, DD, DD);
        gemm_bf16<<<ggrid, blk, 0, stream>>>(hb, Ws_l, bsb + l * DD, skipb, NN, DD, DD);

        qe_kernel<<<dim3((NN * 64) / 256), blk, 0, stream>>>(qb, We_l, Qe);
        edge_alpha<<<dim3(EE / 4), blk, 0, stream>>>(qb, kb, Qe, ef, ei, alpha);
        node_soft<<<dim3((NN * HH + 255) / 256), blk, 0, stream>>>(rowptr, eids, alpha);
        node_gather<<<dim3(NN / 4), blk, 0, stream>>>(rowptr, eids, ei, vb, skipb,
                                                      alpha, ef, We_l, hb, (l < 2) ? 1 : 0);
    }

    ln_pool<<<dim3(40), blk, 0, stream>>>(hb, lngb, lnbb, partial);
    final_kernel<<<dim3(3), blk, 0, stream>>>(partial, d_out, flag);
}

// Round 3
// 929.791 us; speedup vs baseline: 1.8087x; 1.8087x over previous
//
#include <hip/hip_runtime.h>
#include <hip/hip_bf16.h>
#include <math.h>
#include <stdint.h>

#define NN 10000
#define EE 100000
#define DD 768
#define HH 4
#define CC 192
#define EDIM 16
#define NREL 10
#define MP 10112           // NN padded to multiple of 128 for GEMM tiles
#define NQKV 3072          // fused output width: [q|k|v|skip]
#define SCALE 0.07216878364870322f   // 1/sqrt(192)

using short8  = __attribute__((ext_vector_type(8))) short;
using floatx4 = __attribute__((ext_vector_type(4))) float;

// ---------------- helpers ----------------

__device__ __forceinline__ float waveRedSum(float v) {
#pragma unroll
    for (int m = 32; m > 0; m >>= 1) v += __shfl_xor(v, m);
    return v;
}

__device__ __forceinline__ __hip_bfloat16 rd_any(const void* p, long long j, int bf) {
    if (bf) return ((const __hip_bfloat16*)p)[j];
    return __float2bfloat16(((const float*)p)[j]);
}

// async global->LDS, 16B per lane; LDS dest must be wave-uniform base + lane*16
__device__ __forceinline__ void gload16(const __hip_bfloat16* g, __hip_bfloat16* l) {
    __builtin_amdgcn_global_load_lds(
        (const __attribute__((address_space(1))) unsigned int*)g,
        (__attribute__((address_space(3))) unsigned int*)l, 16, 0, 0);
}

// ---------------- dtype detection ----------------
__global__ void detect_kernel(const void* edge_attr, int* flag) {
    const unsigned short* p = (const unsigned short*)edge_attr;
    int t = threadIdx.x;
    int nz = (p[4 * t] != 0) ? 1 : 0;
    unsigned long long m = __ballot(nz);
    if (t == 0) *flag = (__popcll(m) > 8) ? 1 : 0;
}

// ---------------- input conversion ----------------

__global__ __launch_bounds__(256) void cvt_big(
    const void* x, const void* We, const int* flag,
    __hip_bfloat16* hb, __hip_bfloat16* Web) {
    long long i = (long long)blockIdx.x * 256 + threadIdx.x;
    int bf = *flag;
    const long long NX = (long long)NN * DD;       // 7,680,000
    const long long NE2 = 3LL * EDIM * DD;         // 36,864
    if (i < NX) { hb[i] = rd_any(x, i, bf); return; } i -= NX;
    if (i < NE2) { Web[i] = rd_any(We, i, bf); return; } i -= NE2;
    if (i < (long long)(MP - NN) * DD) hb[(long long)NN * DD + i] = __float2bfloat16(0.0f);
}

// per-layer transposed fused weight: Wt[n][k], n: [q|k|v|skip]
__global__ __launch_bounds__(256) void wt_kernel(
    const void* Wq, const void* Wk, const void* Wv, const void* Ws,
    const int* flag, int l, __hip_bfloat16* Wt) {
    int idx = blockIdx.x * 256 + threadIdx.x;
    if (idx >= NQKV * DD) return;
    int n = idx / DD, k = idx % DD;
    const void* src; long long off;
    long long lb = (long long)l * DD * DD;
    if (n < 768)       { src = Wq; off = lb + (long long)k * DD + n; }
    else if (n < 1536) { src = Wk; off = lb + (long long)k * DD + (n - 768); }
    else if (n < 2304) { src = Wv; off = lb + (long long)k * DD + (n - 1536); }
    else               { src = Ws; off = lb + (long long)k * DD + (n - 2304); }
    Wt[idx] = rd_any(src, off, *flag);
}

__global__ __launch_bounds__(256) void cvt_small(
    const void* ea, const void* rel, const void* Wed, const void* bed,
    const void* bk, const void* bq, const void* bv, const void* bs,
    const void* lg, const void* lb, const int* flag,
    __hip_bfloat16* eab, __hip_bfloat16* relb, __hip_bfloat16* Wedb,
    __hip_bfloat16* bedb, __hip_bfloat16* ballb, __hip_bfloat16* lgb,
    __hip_bfloat16* lbb) {
    long long i = (long long)blockIdx.x * 256 + threadIdx.x;
    int bf = *flag;
    if (i < 2LL * EE) { eab[i] = rd_any(ea, i, bf); return; } i -= 2LL * EE;
    if (i < NREL * (EDIM - 1)) { relb[i] = rd_any(rel, i, bf); return; } i -= NREL * (EDIM - 1);
    if (i < EDIM * EDIM) { Wedb[i] = rd_any(Wed, i, bf); return; } i -= EDIM * EDIM;
    if (i < EDIM) { bedb[i] = rd_any(bed, i, bf); return; } i -= EDIM;
    if (i < 3 * NQKV) {
        int l = (int)(i / NQKV), c = (int)(i % NQKV);
        const void* src; long long off;
        if (c < 768)       { src = bq; off = (long long)l * DD + c; }
        else if (c < 1536) { src = bk; off = (long long)l * DD + (c - 768); }
        else if (c < 2304) { src = bv; off = (long long)l * DD + (c - 1536); }
        else               { src = bs; off = (long long)l * DD + (c - 2304); }
        ballb[i] = rd_any(src, off, bf); return;
    } i -= 3 * NQKV;
    if (i < DD) { lgb[i] = rd_any(lg, i, bf); return; } i -= DD;
    if (i < DD) { lbb[i] = rd_any(lb, i, bf); return; }
}

// ---------------- CSR build (incoming edges per dst) ----------------

__global__ __launch_bounds__(256) void zero_counts(int* counts) {
    int i = blockIdx.x * 256 + threadIdx.x;
    if (i < NN) counts[i] = 0;
}

__global__ __launch_bounds__(256) void count_kernel(const int* ei, int* counts) {
    int e = blockIdx.x * 256 + threadIdx.x;
    if (e < EE) atomicAdd(&counts[ei[EE + e]], 1);
}

// single-pass 3-phase scan: 256 threads, 40 elems each (NN = 250*40)
__global__ __launch_bounds__(256) void scan_kernel(const int* counts, int* rowptr) {
    __shared__ int sdata[256];
    int t = threadIdx.x;
    int base = t * 40;
    int cnt = (base < NN) ? min(40, NN - base) : 0;
    int s = 0;
    for (int i = 0; i < cnt; i++) s += counts[base + i];
    sdata[t] = s;
    __syncthreads();
    for (int off = 1; off < 256; off <<= 1) {
        int add = (t >= off) ? sdata[t - off] : 0;
        __syncthreads();
        sdata[t] += add;
        __syncthreads();
    }
    int run = sdata[t] - s;  // exclusive prefix
    for (int i = 0; i < cnt; i++) {
        run += counts[base + i];
        rowptr[base + i + 1] = run;
    }
    if (t == 0) rowptr[0] = 0;
}

__global__ __launch_bounds__(256) void cursor_kernel(const int* rowptr, int* cursor) {
    int i = blockIdx.x * 256 + threadIdx.x;
    if (i < NN) cursor[i] = rowptr[i];
}

__global__ __launch_bounds__(256) void fill_kernel(const int* ei, int* cursor, int* eids) {
    int e = blockIdx.x * 256 + threadIdx.x;
    if (e < EE) {
        int d = ei[EE + e];
        int pos = atomicAdd(&cursor[d], 1);
        eids[pos] = e;
    }
}

// ---------------- edge features ----------------

__global__ __launch_bounds__(256) void ef_kernel(
    const __hip_bfloat16* __restrict__ eab, const __hip_bfloat16* __restrict__ relb,
    const __hip_bfloat16* __restrict__ Wedb, const __hip_bfloat16* __restrict__ bedb,
    float* __restrict__ ef) {
    int idx = blockIdx.x * 256 + threadIdx.x;
    if (idx >= EE * EDIM) return;
    int e = idx >> 4, j = idx & 15;
    int rid = (int)((float)eab[e * 2 + 0]);
    rid = min(max(rid, 0), NREL - 1);
    float w = (float)eab[e * 2 + 1];
    float s = (float)bedb[j];
#pragma unroll
    for (int i = 0; i < 15; i++)
        s += (float)relb[rid * 15 + i] * (float)Wedb[i * EDIM + j];
    s += w * (float)Wedb[15 * EDIM + j];
    ef[idx] = s;
}

// ---------------- fused GEMM: C[10000,3072] = A[MP,768] @ Bt[3072,768]^T + bias ----------------
// m97-style: 128x128 tile, BK=32, async global_load_lds width-16 staging.

__global__ __launch_bounds__(256) void gemm_fused(
    const __hip_bfloat16* __restrict__ A, const __hip_bfloat16* __restrict__ Bt,
    const __hip_bfloat16* __restrict__ bias, __hip_bfloat16* __restrict__ C) {
    __shared__ __hip_bfloat16 As[128 * 32];   // [m][k], contiguous (async-copy layout)
    __shared__ __hip_bfloat16 Bs[128 * 32];   // [n][k], contiguous
    const int tid  = threadIdx.x;
    const int wid  = tid >> 6, lane = tid & 63;
    const int quad = lane >> 4, l15 = lane & 15;
    const int m0 = blockIdx.y * 128, n0 = blockIdx.x * 128;
    const int wm = wid >> 1, wn = wid & 1;
    floatx4 acc[4][4] = {};
    for (int k0 = 0; k0 < DD; k0 += 32) {
#pragma unroll
        for (int j = 0; j < 2; j++) {
            int c = j * 256 + tid;            // chunk index, 16B each
            int r = c >> 2, kc = (c & 3) << 3;
            gload16(A + (size_t)(m0 + r) * DD + k0 + kc, As + c * 8);
            gload16(Bt + (size_t)(n0 + r) * DD + k0 + kc, Bs + c * 8);
        }
        __syncthreads();
        short8 a[4], b[4];
#pragma unroll
        for (int mt = 0; mt < 4; mt++)
            a[mt] = *(const short8*)(As + (wm * 64 + mt * 16 + l15) * 32 + quad * 8);
#pragma unroll
        for (int nt = 0; nt < 4; nt++)
            b[nt] = *(const short8*)(Bs + (wn * 64 + nt * 16 + l15) * 32 + quad * 8);
#pragma unroll
        for (int mt = 0; mt < 4; mt++)
#pragma unroll
            for (int nt = 0; nt < 4; nt++)
                acc[mt][nt] = __builtin_amdgcn_mfma_f32_16x16x32_bf16(a[mt], b[nt], acc[mt][nt], 0, 0, 0);
        __syncthreads();
    }
#pragma unroll
    for (int nt = 0; nt < 4; nt++) {
        int col = n0 + wn * 64 + nt * 16 + l15;
        float bval = (float)bias[col];
#pragma unroll
        for (int mt = 0; mt < 4; mt++) {
#pragma unroll
            for (int r = 0; r < 4; r++) {
                int row = m0 + wm * 64 + mt * 16 + quad * 4 + r;
                if (row < NN)
                    C[(size_t)row * NQKV + col] = __float2bfloat16(acc[mt][nt][r] + bval);
            }
        }
    }
}

// ---------------- attention ----------------
// qkvs row layout: [q(0) | k(768) | v(1536) | skip(2304)]

__global__ __launch_bounds__(256) void qe_kernel(
    const __hip_bfloat16* __restrict__ qkvs, const __hip_bfloat16* __restrict__ Wel,
    float* __restrict__ Qe) {
    int idx = blockIdx.x * 256 + threadIdx.x;
    if (idx >= NN * HH * EDIM) return;
    int n = idx >> 6, hj = idx & 63, hh = hj >> 4, j = hj & 15;
    const __hip_bfloat16* qrow = qkvs + (size_t)n * NQKV + hh * CC;
    const __hip_bfloat16* wrow = Wel + (size_t)j * DD + hh * CC;
    float s = 0.f;
    for (int c = 0; c < CC; c++) s += (float)qrow[c] * (float)wrow[c];
    Qe[idx] = s;
}

__global__ __launch_bounds__(256) void edge_alpha(
    const __hip_bfloat16* __restrict__ qkvs, const float* __restrict__ Qe,
    const float* __restrict__ ef, const int* __restrict__ ei,
    float* __restrict__ alpha) {
    int wv = blockIdx.x * 4 + (threadIdx.x >> 6);
    int lane = threadIdx.x & 63;
    int s = ei[wv], d = ei[EE + wv];
    const __hip_bfloat16* qrow = qkvs + (size_t)d * NQKV;
    const __hip_bfloat16* krow = qkvs + (size_t)s * NQKV + 768;
    float p0 = 0.f, p1 = 0.f, p2 = 0.f, p3 = 0.f;
#pragma unroll
    for (int i = 0; i < 12; i++) {
        int ch = lane + (i << 6);
        float p = (float)qrow[ch] * (float)krow[ch];
        if (i < 3) p0 += p; else if (i < 6) p1 += p; else if (i < 9) p2 += p; else p3 += p;
    }
#pragma unroll
    for (int m = 1; m < 64; m <<= 1) {
        p0 += __shfl_xor(p0, m); p1 += __shfl_xor(p1, m);
        p2 += __shfl_xor(p2, m); p3 += __shfl_xor(p3, m);
    }
    if (lane < 4) {
        float qk = (lane == 0) ? p0 : (lane == 1) ? p1 : (lane == 2) ? p2 : p3;
        const float* Qrow = Qe + (size_t)d * 64 + lane * 16;
        const float* erow = ef + (size_t)wv * 16;
        float qe = 0.f;
#pragma unroll
        for (int j = 0; j < 16; j++) qe += Qrow[j] * erow[j];
        alpha[wv * 4 + lane] = (qk + qe) * SCALE;
    }
}

__global__ __launch_bounds__(256) void node_soft(
    const int* __restrict__ rowptr, const int* __restrict__ eids,
    float* __restrict__ alpha) {
    int idx = blockIdx.x * 256 + threadIdx.x;
    if (idx >= NN * HH) return;
    int n = idx >> 2, hh = idx & 3;
    int s0 = rowptr[n], s1 = rowptr[n + 1];
    float m = -1e30f;
    for (int p = s0; p < s1; p++) m = fmaxf(m, alpha[eids[p] * 4 + hh]);
    float den = 0.f;
    for (int p = s0; p < s1; p++) den += expf(alpha[eids[p] * 4 + hh] - m);
    float inv = 1.0f / (den + 1e-16f);
    for (int p = s0; p < s1; p++) {
        int a = eids[p] * 4 + hh;
        alpha[a] = expf(alpha[a] - m) * inv;
    }
}

__global__ __launch_bounds__(256) void node_gather(
    const int* __restrict__ rowptr, const int* __restrict__ eids,
    const int* __restrict__ ei, const __hip_bfloat16* __restrict__ qkvs,
    const float* __restrict__ anorm, const float* __restrict__ ef,
    const __hip_bfloat16* __restrict__ Wel, __hip_bfloat16* __restrict__ hb,
    int do_gelu) {
    __shared__ float S_l[4][64];
    int wid = threadIdx.x >> 6, lane = threadIdx.x & 63;
    int n = blockIdx.x * 4 + wid;   // grid = 2500 blocks, exact
    int s0 = rowptr[n], s1 = rowptr[n + 1];
    float acc[12];
#pragma unroll
    for (int i = 0; i < 12; i++) acc[i] = 0.f;
    int sh = lane >> 4, sj = lane & 15;
    float sacc = 0.f;
    for (int p = s0; p < s1; p++) {
        int e = eids[p];
        int src = ei[e];
        float a0 = anorm[e * 4 + 0], a1 = anorm[e * 4 + 1];
        float a2 = anorm[e * 4 + 2], a3 = anorm[e * 4 + 3];
        const __hip_bfloat16* vrow = qkvs + (size_t)src * NQKV + 1536;
#pragma unroll
        for (int i = 0; i < 12; i++) {
            int ch = lane + (i << 6);
            float ah = (i < 3) ? a0 : (i < 6) ? a1 : (i < 9) ? a2 : a3;
            acc[i] += ah * (float)vrow[ch];
        }
        float ahS = (sh == 0) ? a0 : (sh == 1) ? a1 : (sh == 2) ? a2 : a3;
        sacc += ahS * ef[(size_t)e * 16 + sj];
    }
    S_l[wid][lane] = sacc;
    __syncthreads();
    const __hip_bfloat16* skrow = qkvs + (size_t)n * NQKV + 2304;
    __hip_bfloat16* hrow = hb + (size_t)n * DD;
#pragma unroll
    for (int i = 0; i < 12; i++) {
        int ch = lane + (i << 6);
        int hh = ch / CC;
        float sv = 0.f;
#pragma unroll
        for (int j = 0; j < 16; j++)
            sv += S_l[wid][hh * 16 + j] * (float)Wel[(size_t)j * DD + ch];
        float val = acc[i] + sv + (float)skrow[ch];
        if (do_gelu) val = 0.5f * val * (1.0f + erff(val * 0.70710678118654752f));
        hrow[ch] = __float2bfloat16(val);
    }
}

// ---------------- LN + mean pool ----------------
// grid 400 blocks, 25 rows each (one row per wave round-robin)

__global__ __launch_bounds__(256) void ln_pool(
    const __hip_bfloat16* __restrict__ hb, const __hip_bfloat16* __restrict__ g,
    const __hip_bfloat16* __restrict__ b, float* __restrict__ partial) {
    __shared__ float sbuf[4][768];
    int grp = blockIdx.x, t = threadIdx.x;
    int wid = t >> 6, lane = t & 63;
    float gv[12], bv[12], acc[12];
#pragma unroll
    for (int i = 0; i < 12; i++) {
        gv[i] = (float)g[lane + i * 64];
        bv[i] = (float)b[lane + i * 64];
        acc[i] = 0.f;
    }
    for (int r = wid; r < 25; r += 4) {
        const __hip_bfloat16* row = hb + (size_t)(grp * 25 + r) * DD;
        float x[12];
        float s = 0.f, q = 0.f;
#pragma unroll
        for (int i = 0; i < 12; i++) {
            x[i] = (float)row[lane + i * 64];
            s += x[i]; q += x[i] * x[i];
        }
#pragma unroll
        for (int m = 32; m > 0; m >>= 1) {
            s += __shfl_xor(s, m); q += __shfl_xor(q, m);
        }
        float mu = s * (1.0f / 768.0f);
        float ms = q * (1.0f / 768.0f);
        float inv = 1.0f / sqrtf(ms - mu * mu + 1e-5f);
#pragma unroll
        for (int i = 0; i < 12; i++)
            acc[i] += (x[i] - mu) * inv * gv[i] + bv[i];
    }
#pragma unroll
    for (int i = 0; i < 12; i++) sbuf[wid][lane + i * 64] = acc[i];
    __syncthreads();
#pragma unroll
    for (int j = 0; j < 3; j++) {
        int col = t + j * 256;
        partial[(size_t)grp * DD + col] =
            sbuf[0][col] + sbuf[1][col] + sbuf[2][col] + sbuf[3][col];
    }
}

__global__ __launch_bounds__(256) void pool1_kernel(
    const float* __restrict__ partial, float* __restrict__ partial2) {
    int idx = blockIdx.x * 256 + threadIdx.x;     // 16*768 = 12288
    if (idx >= 16 * DD) return;
    int g2 = idx / DD, col = idx % DD;
    float s = 0.f;
    for (int r = 0; r < 25; r++) s += partial[(size_t)(g2 * 25 + r) * DD + col];
    partial2[idx] = s;
}

__global__ __launch_bounds__(256) void pool2_kernel(
    const float* __restrict__ partial2, void* __restrict__ out,
    const int* __restrict__ flag) {
    int dd = blockIdx.x * 256 + threadIdx.x;
    if (dd >= DD) return;
    float s = 0.f;
#pragma unroll
    for (int g2 = 0; g2 < 16; g2++) s += partial2[g2 * DD + dd];
    s *= (1.0f / 10000.0f);
    if (*flag) ((__hip_bfloat16*)out)[dd] = __float2bfloat16(s);
    else ((float*)out)[dd] = s;
}

// ---------------- launch ----------------

extern "C" void kernel_launch(void* const* d_in, const int* in_sizes, int n_in,
                              void* d_out, int out_size, void* d_ws, size_t ws_size,
                              hipStream_t stream) {
    const void* x         = d_in[0];
    const void* edge_attr = d_in[1];
    const int*  ei        = (const int*)d_in[2];
    const void* rel_emb   = d_in[3];
    const void* W_edge    = d_in[4];
    const void* b_edge    = d_in[5];
    const void* Wk        = d_in[6];
    const void* bk        = d_in[7];
    const void* Wq        = d_in[8];
    const void* bq        = d_in[9];
    const void* Wv        = d_in[10];
    const void* bv        = d_in[11];
    const void* We        = d_in[12];
    const void* Wskip     = d_in[13];
    const void* bskip     = d_in[14];
    const void* ln_g      = d_in[15];
    const void* ln_b      = d_in[16];

    char* ws = (char*)d_ws;
    // ---- workspace layout (~94.6 MB total) ----
    int*   flag    = (int*)(ws + 0);
    int*   counts  = (int*)(ws + 256);        // 40,000
    int*   rowptr  = (int*)(ws + 40448);      // 40,004
    int*   cursor  = (int*)(ws + 80640);      // 40,000
    int*   eids    = (int*)(ws + 120832);     // 400,000
    float* ef      = (float*)(ws + 520960);   // 6,400,000
    float* Qe      = (float*)(ws + 6921216);  // 2,560,000
    float* alpha   = (float*)(ws + 9481216);  // 1,600,000
    float* partial = (float*)(ws + 11081216); // 1,228,800
    float* partial2= (float*)(ws + 12310016); // 49,152
    __hip_bfloat16* eab   = (__hip_bfloat16*)(ws + 12359168);  // 400,000
    __hip_bfloat16* relb  = (__hip_bfloat16*)(ws + 12759168);  // 300
    __hip_bfloat16* Wedb  = (__hip_bfloat16*)(ws + 12759488);  // 512
    __hip_bfloat16* bedb  = (__hip_bfloat16*)(ws + 12760000);  // 32
    __hip_bfloat16* ballb = (__hip_bfloat16*)(ws + 12760064);  // 18,432
    __hip_bfloat16* lngb  = (__hip_bfloat16*)(ws + 12778496);  // 1,536
    __hip_bfloat16* lnbb  = (__hip_bfloat16*)(ws + 12780032);  // 1,536
    __hip_bfloat16* Web   = (__hip_bfloat16*)(ws + 12781568);  // 73,728
    __hip_bfloat16* hb    = (__hip_bfloat16*)(ws + 12855296);  // 15,532,032
    __hip_bfloat16* Wt    = (__hip_bfloat16*)(ws + 28387328);  // 4,718,592
    __hip_bfloat16* qkvs  = (__hip_bfloat16*)(ws + 33105920);  // 61,440,000 -> 94,545,920

    dim3 blk(256);

    detect_kernel<<<dim3(1), dim3(64), 0, stream>>>(edge_attr, flag);

    {
        long long tot = (long long)NN * DD + 3LL * EDIM * DD + (long long)(MP - NN) * DD;
        cvt_big<<<dim3((unsigned)((tot + 255) / 256)), blk, 0, stream>>>(x, We, flag, hb, Web);
    }
    {
        long long tot = 2LL * EE + NREL * (EDIM - 1) + EDIM * EDIM + EDIM
                        + 3LL * NQKV + 2LL * DD;
        cvt_small<<<dim3((unsigned)((tot + 255) / 256)), blk, 0, stream>>>(
            edge_attr, rel_emb, W_edge, b_edge, bk, bq, bv, bskip, ln_g, ln_b,
            flag, eab, relb, Wedb, bedb, ballb, lngb, lnbb);
    }

    // CSR build
    zero_counts<<<dim3(40), blk, 0, stream>>>(counts);
    count_kernel<<<dim3((EE + 255) / 256), blk, 0, stream>>>(ei, counts);
    scan_kernel<<<dim3(1), blk, 0, stream>>>(counts, rowptr);
    cursor_kernel<<<dim3(40), blk, 0, stream>>>(rowptr, cursor);
    fill_kernel<<<dim3((EE + 255) / 256), blk, 0, stream>>>(ei, cursor, eids);

    ef_kernel<<<dim3((EE * EDIM) / 256), blk, 0, stream>>>(eab, relb, Wedb, bedb, ef);

    for (int l = 0; l < 3; l++) {
        const __hip_bfloat16* We_l = Web + (size_t)l * EDIM * DD;

        wt_kernel<<<dim3((NQKV * DD) / 256), blk, 0, stream>>>(Wq, Wk, Wv, Wskip, flag, l, Wt);
        gemm_fused<<<dim3(NQKV / 128, MP / 128), blk, 0, stream>>>(hb, Wt, ballb + l * NQKV, qkvs);

        qe_kernel<<<dim3((NN * 64) / 256), blk, 0, stream>>>(qkvs, We_l, Qe);
        edge_alpha<<<dim3(EE / 4), blk, 0, stream>>>(qkvs, Qe, ef, ei, alpha);
        node_soft<<<dim3((NN * HH + 255) / 256), blk, 0, stream>>>(rowptr, eids, alpha);
        node_gather<<<dim3(NN / 4), blk, 0, stream>>>(rowptr, eids, ei, qkvs, alpha, ef,
                                                      We_l, hb, (l < 2) ? 1 : 0);
    }

    ln_pool<<<dim3(400), blk, 0, stream>>>(hb, lngb, lnbb, partial);
    pool1_kernel<<<dim3(48), blk, 0, stream>>>(partial, partial2);
    pool2_kernel<<<dim3(3), blk, 0, stream>>>(partial2, d_out, flag);
}

// Round 4
// 728.306 us; speedup vs baseline: 2.3091x; 1.2766x over previous
//
#include <hip/hip_runtime.h>
#include <hip/hip_bf16.h>
#include <math.h>
#include <stdint.h>

#define NN 10000
#define EE 100000
#define DD 768
#define HH 4
#define CC 192
#define EDIM 16
#define NREL 10
#define MP 10112           // NN padded to multiple of 128 for GEMM tiles
#define NQKV 3072          // fused output width: [q|k|v|skip]
#define SCALE 0.07216878364870322f   // 1/sqrt(192)

using short8  = __attribute__((ext_vector_type(8))) short;
using floatx4 = __attribute__((ext_vector_type(4))) float;

// ---------------- helpers ----------------

__device__ __forceinline__ float b2f(short u) {
    union { unsigned int i; float f; } t;
    t.i = ((unsigned int)(unsigned short)u) << 16;
    return t.f;
}

__device__ __forceinline__ short f2b(float f) {
    __hip_bfloat16 h = __float2bfloat16(f);
    short r;
    __builtin_memcpy(&r, &h, 2);
    return r;
}

__device__ __forceinline__ __hip_bfloat16 rd_any(const void* p, long long j, int bf) {
    if (bf) return ((const __hip_bfloat16*)p)[j];
    return __float2bfloat16(((const float*)p)[j]);
}

// async global->LDS, 16B per lane; LDS dest must be wave-uniform base + lane*16
__device__ __forceinline__ void gload16(const __hip_bfloat16* g, __hip_bfloat16* l) {
    __builtin_amdgcn_global_load_lds(
        (const __attribute__((address_space(1))) unsigned int*)g,
        (__attribute__((address_space(3))) unsigned int*)l, 16, 0, 0);
}

// ---------------- dtype detection ----------------
__global__ void detect_kernel(const void* edge_attr, int* flag) {
    const unsigned short* p = (const unsigned short*)edge_attr;
    int t = threadIdx.x;
    int nz = (p[4 * t] != 0) ? 1 : 0;
    unsigned long long m = __ballot(nz);
    if (t == 0) *flag = (__popcll(m) > 8) ? 1 : 0;
}

// ---------------- input conversion ----------------

__global__ __launch_bounds__(256) void cvt_big(
    const void* x, const void* We, const int* flag,
    __hip_bfloat16* hb, __hip_bfloat16* Web) {
    long long i = (long long)blockIdx.x * 256 + threadIdx.x;
    int bf = *flag;
    const long long NX = (long long)NN * DD;
    const long long NE2 = 3LL * EDIM * DD;
    if (i < NX) { hb[i] = rd_any(x, i, bf); return; } i -= NX;
    if (i < NE2) { Web[i] = rd_any(We, i, bf); return; } i -= NE2;
    if (i < (long long)(MP - NN) * DD) hb[(long long)NN * DD + i] = __float2bfloat16(0.0f);
}

__global__ __launch_bounds__(256) void cvt_small(
    const void* ea, const void* rel, const void* Wed, const void* bed,
    const void* bk, const void* bq, const void* bv, const void* bs,
    const void* lg, const void* lb, const int* flag,
    __hip_bfloat16* eab, __hip_bfloat16* relb, __hip_bfloat16* Wedb,
    __hip_bfloat16* bedb, __hip_bfloat16* ballb, __hip_bfloat16* lgb,
    __hip_bfloat16* lbb) {
    long long i = (long long)blockIdx.x * 256 + threadIdx.x;
    int bf = *flag;
    if (i < 2LL * EE) { eab[i] = rd_any(ea, i, bf); return; } i -= 2LL * EE;
    if (i < NREL * (EDIM - 1)) { relb[i] = rd_any(rel, i, bf); return; } i -= NREL * (EDIM - 1);
    if (i < EDIM * EDIM) { Wedb[i] = rd_any(Wed, i, bf); return; } i -= EDIM * EDIM;
    if (i < EDIM) { bedb[i] = rd_any(bed, i, bf); return; } i -= EDIM;
    if (i < 3 * NQKV) {
        int l = (int)(i / NQKV), c = (int)(i % NQKV);
        const void* src; long long off;
        if (c < 768)       { src = bq; off = (long long)l * DD + c; }
        else if (c < 1536) { src = bk; off = (long long)l * DD + (c - 768); }
        else if (c < 2304) { src = bv; off = (long long)l * DD + (c - 1536); }
        else               { src = bs; off = (long long)l * DD + (c - 2304); }
        ballb[i] = rd_any(src, off, bf); return;
    } i -= 3 * NQKV;
    if (i < DD) { lgb[i] = rd_any(lg, i, bf); return; } i -= DD;
    if (i < DD) { lbb[i] = rd_any(lb, i, bf); return; }
}

// all-layer fused transposed weights: Wt3[l][n][k], n: [q|k|v|skip]
__global__ __launch_bounds__(256) void wt_all(
    const void* Wq, const void* Wk, const void* Wv, const void* Ws,
    const int* flag, __hip_bfloat16* Wt3) {
    __shared__ __hip_bfloat16 tile[32][33];
    int mm = blockIdx.y;            // l*4 + m
    int l = mm >> 2, m = mm & 3;
    const void* src = (m == 0) ? Wq : (m == 1) ? Wk : (m == 2) ? Wv : Ws;
    int bx = blockIdx.x;            // 24*24 tiles of 32x32
    int tr = bx / 24, tc = bx % 24;
    int k0 = tr * 32, c0 = tc * 32;
    int t = threadIdx.x;
    int rr = t >> 5, cc = t & 31;
    int bf = *flag;
    long long base = (long long)l * DD * DD;
#pragma unroll
    for (int p = 0; p < 4; p++)
        tile[p * 8 + rr][cc] =
            rd_any(src, base + (long long)(k0 + p * 8 + rr) * DD + c0 + cc, bf);
    __syncthreads();
    __hip_bfloat16* dst = Wt3 + (size_t)l * NQKV * DD + (size_t)(m * 768 + c0) * DD + k0;
#pragma unroll
    for (int p = 0; p < 4; p++)
        dst[(size_t)(p * 8 + rr) * DD + cc] = tile[cc][p * 8 + rr];
}

// ---------------- CSR build (incoming edges per dst) ----------------

__global__ __launch_bounds__(256) void zero_counts(int* counts) {
    int i = blockIdx.x * 256 + threadIdx.x;
    if (i < NN) counts[i] = 0;
}

__global__ __launch_bounds__(256) void count_kernel(const int* ei, int* counts) {
    int e = blockIdx.x * 256 + threadIdx.x;
    if (e < EE) atomicAdd(&counts[ei[EE + e]], 1);
}

__global__ __launch_bounds__(256) void scan_kernel(const int* counts, int* rowptr) {
    __shared__ int sdata[256];
    int t = threadIdx.x;
    int base = t * 40;
    int cnt = (base < NN) ? min(40, NN - base) : 0;
    int s = 0;
    for (int i = 0; i < cnt; i++) s += counts[base + i];
    sdata[t] = s;
    __syncthreads();
    for (int off = 1; off < 256; off <<= 1) {
        int add = (t >= off) ? sdata[t - off] : 0;
        __syncthreads();
        sdata[t] += add;
        __syncthreads();
    }
    int run = sdata[t] - s;  // exclusive prefix
    for (int i = 0; i < cnt; i++) {
        run += counts[base + i];
        rowptr[base + i + 1] = run;
    }
    if (t == 0) rowptr[0] = 0;
}

__global__ __launch_bounds__(256) void cursor_kernel(const int* rowptr, int* cursor) {
    int i = blockIdx.x * 256 + threadIdx.x;
    if (i < NN) cursor[i] = rowptr[i];
}

__global__ __launch_bounds__(256) void fill_kernel(const int* ei, int* cursor,
                                                   int* eids, int* esrc) {
    int e = blockIdx.x * 256 + threadIdx.x;
    if (e < EE) {
        int d = ei[EE + e];
        int pos = atomicAdd(&cursor[d], 1);
        eids[pos] = e;
        esrc[pos] = ei[e];
    }
}

// ---------------- edge features ----------------

__global__ __launch_bounds__(256) void ef_kernel(
    const __hip_bfloat16* __restrict__ eab, const __hip_bfloat16* __restrict__ relb,
    const __hip_bfloat16* __restrict__ Wedb, const __hip_bfloat16* __restrict__ bedb,
    float* __restrict__ ef) {
    int idx = blockIdx.x * 256 + threadIdx.x;
    if (idx >= EE * EDIM) return;
    int e = idx >> 4, j = idx & 15;
    int rid = (int)((float)eab[e * 2 + 0]);
    rid = min(max(rid, 0), NREL - 1);
    float w = (float)eab[e * 2 + 1];
    float s = (float)bedb[j];
#pragma unroll
    for (int i = 0; i < 15; i++)
        s += (float)relb[rid * 15 + i] * (float)Wedb[i * EDIM + j];
    s += w * (float)Wedb[15 * EDIM + j];
    ef[idx] = s;
}

// ---------------- fused GEMM: C[NN,3072] = A[MP,768] @ Wt[3072,768]^T + bias ----
// 128x128 tile, BK=32, async width-16 staging, XOR bank swizzle, LDS-bounce store.

__global__ __launch_bounds__(256) void gemm_fused(
    const __hip_bfloat16* __restrict__ A, const __hip_bfloat16* __restrict__ Bt,
    const __hip_bfloat16* __restrict__ bias, __hip_bfloat16* __restrict__ C) {
    __shared__ __hip_bfloat16 As[128 * 32];   // 8 KB
    __shared__ __hip_bfloat16 Bs[128 * 32];   // 8 KB
    const int tid  = threadIdx.x;
    const int wid  = tid >> 6, lane = tid & 63;
    const int quad = lane >> 4, l15 = lane & 15;
    const int m0 = blockIdx.y * 128, n0 = blockIdx.x * 128;
    const int wm = wid >> 1, wn = wid & 1;
    floatx4 acc[4][4] = {};
    for (int k0 = 0; k0 < DD; k0 += 32) {
#pragma unroll
        for (int j = 0; j < 2; j++) {
            int c = j * 256 + tid;            // chunk index, 16B each
            int r = c >> 2, s = c & 3;
            int ks = s ^ ((r + (r >> 2)) & 3);   // source k-chunk (XOR swizzle)
            gload16(A + (size_t)(m0 + r) * DD + k0 + ks * 8, As + c * 8);
            gload16(Bt + (size_t)(n0 + r) * DD + k0 + ks * 8, Bs + c * 8);
        }
        __syncthreads();
        short8 a[4], b[4];
#pragma unroll
        for (int mt = 0; mt < 4; mt++) {
            int R = wm * 64 + mt * 16 + l15;
            int sw = quad ^ ((R + (R >> 2)) & 3);
            a[mt] = *(const short8*)(As + R * 32 + sw * 8);
        }
#pragma unroll
        for (int nt = 0; nt < 4; nt++) {
            int R = wn * 64 + nt * 16 + l15;
            int sw = quad ^ ((R + (R >> 2)) & 3);
            b[nt] = *(const short8*)(Bs + R * 32 + sw * 8);
        }
#pragma unroll
        for (int mt = 0; mt < 4; mt++)
#pragma unroll
            for (int nt = 0; nt < 4; nt++)
                acc[mt][nt] = __builtin_amdgcn_mfma_f32_16x16x32_bf16(a[mt], b[nt], acc[mt][nt], 0, 0, 0);
        __syncthreads();
    }
    // epilogue: per mt, stage 32 rows x 128 cols (bf16) into As, then 16B stores
    __hip_bfloat16* stage = As;
    float bv[4];
#pragma unroll
    for (int nt = 0; nt < 4; nt++) bv[nt] = (float)bias[n0 + wn * 64 + nt * 16 + l15];
    const int rr = tid >> 3, ccs = (tid & 7) * 16;
    const int grow = m0 + (rr >> 4) * 64 + (rr & 15);
    for (int mt = 0; mt < 4; mt++) {
#pragma unroll
        for (int nt = 0; nt < 4; nt++) {
            int col = wn * 64 + nt * 16 + l15;
#pragma unroll
            for (int r = 0; r < 4; r++) {
                int lr = wm * 16 + quad * 4 + r;
                stage[lr * 128 + col] = __float2bfloat16(acc[mt][nt][r] + bv[nt]);
            }
        }
        __syncthreads();
        int row = grow + mt * 16;
        if (row < NN) {
            const short8* sp = (const short8*)(stage + rr * 128 + ccs);
            short8* dp = (short8*)(C + (size_t)row * NQKV + n0 + ccs);
            dp[0] = sp[0]; dp[1] = sp[1];
        }
        __syncthreads();
    }
}

// ---------------- attention ----------------
// qkvs row layout: [q(0) | k(768) | v(1536) | skip(2304)]

// Qe[n,h,j] = dot(q[n, h*C:(h+1)*C], We_l[j, h*C:(h+1)*C])
__global__ __launch_bounds__(256) void qe_kernel(
    const __hip_bfloat16* __restrict__ qkvs, const __hip_bfloat16* __restrict__ Wel,
    float* __restrict__ Qe) {
    int idx = blockIdx.x * 256 + threadIdx.x;
    if (idx >= NN * HH * EDIM) return;
    int n = idx >> 6, hj = idx & 63, hh = hj >> 4, j = hj & 15;
    const __hip_bfloat16* qrow = qkvs + (size_t)n * NQKV + hh * CC;
    const __hip_bfloat16* wrow = Wel + (size_t)j * DD + hh * CC;
    float s = 0.f;
    for (int c = 0; c < CC; c++) s += (float)qrow[c] * (float)wrow[c];
    Qe[idx] = s;
}

// one wave per node: fused alpha + online softmax + gather + S@We + skip + gelu.
// lane owns channels [lane*12, lane*12+12), all within head (lane>>4).
__global__ __launch_bounds__(256) void node_attn(
    const int* __restrict__ rowptr, const int* __restrict__ eids,
    const int* __restrict__ esrc, const __hip_bfloat16* __restrict__ qkvs,
    const float* __restrict__ Qe, const float* __restrict__ ef,
    const __hip_bfloat16* __restrict__ Wel, __hip_bfloat16* __restrict__ hb,
    int do_gelu) {
    const int wid = threadIdx.x >> 6, lane = threadIdx.x & 63;
    const int n = blockIdx.x * 4 + wid;
    const int sj = lane & 15;
    const int s0 = rowptr[n], s1 = rowptr[n + 1];
    float q[12];
    {
        const short4* qp = (const short4*)(qkvs + (size_t)n * NQKV + lane * 12);
        short4 a = qp[0], b = qp[1], c = qp[2];
        q[0] = b2f(a.x); q[1] = b2f(a.y); q[2]  = b2f(a.z); q[3]  = b2f(a.w);
        q[4] = b2f(b.x); q[5] = b2f(b.y); q[6]  = b2f(b.z); q[7]  = b2f(b.w);
        q[8] = b2f(c.x); q[9] = b2f(c.y); q[10] = b2f(c.z); q[11] = b2f(c.w);
    }
    float qe_l = Qe[n * 64 + lane];
    float m = -INFINITY, lsum = 0.f, sacc = 0.f;
    float acc[12];
#pragma unroll
    for (int i = 0; i < 12; i++) acc[i] = 0.f;
    for (int p = s0; p < s1; p++) {
        int e = eids[p], src = esrc[p];
        const short4* kp = (const short4*)(qkvs + (size_t)src * NQKV + 768 + lane * 12);
        const short4* vp = (const short4*)(qkvs + (size_t)src * NQKV + 1536 + lane * 12);
        short4 ka = kp[0], kb = kp[1], kc = kp[2];
        short4 va = vp[0], vb = vp[1], vc = vp[2];
        float efv = ef[(size_t)e * 16 + sj];
        float kv[12], vv[12];
        kv[0] = b2f(ka.x); kv[1] = b2f(ka.y); kv[2]  = b2f(ka.z); kv[3]  = b2f(ka.w);
        kv[4] = b2f(kb.x); kv[5] = b2f(kb.y); kv[6]  = b2f(kb.z); kv[7]  = b2f(kb.w);
        kv[8] = b2f(kc.x); kv[9] = b2f(kc.y); kv[10] = b2f(kc.z); kv[11] = b2f(kc.w);
        vv[0] = b2f(va.x); vv[1] = b2f(va.y); vv[2]  = b2f(va.z); vv[3]  = b2f(va.w);
        vv[4] = b2f(vb.x); vv[5] = b2f(vb.y); vv[6]  = b2f(vb.z); vv[7]  = b2f(vb.w);
        vv[8] = b2f(vc.x); vv[9] = b2f(vc.y); vv[10] = b2f(vc.z); vv[11] = b2f(vc.w);
        float part = 0.f;
#pragma unroll
        for (int i = 0; i < 12; i++) part += q[i] * kv[i];
        part += __shfl_xor(part, 1); part += __shfl_xor(part, 2);
        part += __shfl_xor(part, 4); part += __shfl_xor(part, 8);
        float et = qe_l * efv;
        et += __shfl_xor(et, 1); et += __shfl_xor(et, 2);
        et += __shfl_xor(et, 4); et += __shfl_xor(et, 8);
        float a = (part + et) * SCALE;
        float nm = fmaxf(m, a);
        float sc = __expf(m - nm);
        float w  = __expf(a - nm);
        lsum = lsum * sc + w;
        m = nm;
#pragma unroll
        for (int i = 0; i < 12; i++) acc[i] = acc[i] * sc + w * vv[i];
        sacc = sacc * sc + w * efv;
    }
    float inv = 1.0f / (lsum + 1e-16f);
#pragma unroll
    for (int i = 0; i < 12; i++) acc[i] *= inv;
    float sS = sacc * inv;
    // skip connection
    {
        const short4* sp = (const short4*)(qkvs + (size_t)n * NQKV + 2304 + lane * 12);
        short4 a = sp[0], b = sp[1], c = sp[2];
        acc[0] += b2f(a.x); acc[1] += b2f(a.y); acc[2]  += b2f(a.z); acc[3]  += b2f(a.w);
        acc[4] += b2f(b.x); acc[5] += b2f(b.y); acc[6]  += b2f(b.z); acc[7]  += b2f(b.w);
        acc[8] += b2f(c.x); acc[9] += b2f(c.y); acc[10] += b2f(c.z); acc[11] += b2f(c.w);
    }
    // + S @ We (per-head 16-dim): S[h][j] broadcast via shfl
    const int hbase = lane & 48;   // h*16
#pragma unroll
    for (int j = 0; j < 16; j++) {
        float sv = __shfl(sS, hbase + j);
        const short4* wp = (const short4*)(Wel + (size_t)j * DD + lane * 12);
        short4 a = wp[0], b = wp[1], c = wp[2];
        acc[0] += sv * b2f(a.x); acc[1] += sv * b2f(a.y);
        acc[2] += sv * b2f(a.z); acc[3] += sv * b2f(a.w);
        acc[4] += sv * b2f(b.x); acc[5] += sv * b2f(b.y);
        acc[6] += sv * b2f(b.z); acc[7] += sv * b2f(b.w);
        acc[8] += sv * b2f(c.x); acc[9] += sv * b2f(c.y);
        acc[10] += sv * b2f(c.z); acc[11] += sv * b2f(c.w);
    }
    if (do_gelu) {
#pragma unroll
        for (int i = 0; i < 12; i++)
            acc[i] = 0.5f * acc[i] * (1.0f + erff(acc[i] * 0.70710678118654752f));
    }
    short4 o0, o1, o2;
    o0.x = f2b(acc[0]); o0.y = f2b(acc[1]); o0.z = f2b(acc[2]); o0.w = f2b(acc[3]);
    o1.x = f2b(acc[4]); o1.y = f2b(acc[5]); o1.z = f2b(acc[6]); o1.w = f2b(acc[7]);
    o2.x = f2b(acc[8]); o2.y = f2b(acc[9]); o2.z = f2b(acc[10]); o2.w = f2b(acc[11]);
    short4* hp = (short4*)(hb + (size_t)n * DD + lane * 12);
    hp[0] = o0; hp[1] = o1; hp[2] = o2;
}

// ---------------- LN + mean pool ----------------

__global__ __launch_bounds__(256) void ln_pool(
    const __hip_bfloat16* __restrict__ hb, const __hip_bfloat16* __restrict__ g,
    const __hip_bfloat16* __restrict__ b, float* __restrict__ partial) {
    __shared__ float sbuf[4][768];
    int grp = blockIdx.x, t = threadIdx.x;
    int wid = t >> 6, lane = t & 63;
    float gv[12], bv[12], acc[12];
#pragma unroll
    for (int i = 0; i < 12; i++) {
        gv[i] = (float)g[lane + i * 64];
        bv[i] = (float)b[lane + i * 64];
        acc[i] = 0.f;
    }
    for (int r = wid; r < 25; r += 4) {
        const __hip_bfloat16* row = hb + (size_t)(grp * 25 + r) * DD;
        float x[12];
        float s = 0.f, q = 0.f;
#pragma unroll
        for (int i = 0; i < 12; i++) {
            x[i] = (float)row[lane + i * 64];
            s += x[i]; q += x[i] * x[i];
        }
#pragma unroll
        for (int m = 32; m > 0; m >>= 1) {
            s += __shfl_xor(s, m); q += __shfl_xor(q, m);
        }
        float mu = s * (1.0f / 768.0f);
        float ms = q * (1.0f / 768.0f);
        float inv = 1.0f / sqrtf(ms - mu * mu + 1e-5f);
#pragma unroll
        for (int i = 0; i < 12; i++)
            acc[i] += (x[i] - mu) * inv * gv[i] + bv[i];
    }
#pragma unroll
    for (int i = 0; i < 12; i++) sbuf[wid][lane + i * 64] = acc[i];
    __syncthreads();
#pragma unroll
    for (int j = 0; j < 3; j++) {
        int col = t + j * 256;
        partial[(size_t)grp * DD + col] =
            sbuf[0][col] + sbuf[1][col] + sbuf[2][col] + sbuf[3][col];
    }
}

__global__ __launch_bounds__(256) void pool1_kernel(
    const float* __restrict__ partial, float* __restrict__ partial2) {
    int idx = blockIdx.x * 256 + threadIdx.x;     // 16*768
    if (idx >= 16 * DD) return;
    int g2 = idx / DD, col = idx % DD;
    float s = 0.f;
    for (int r = 0; r < 25; r++) s += partial[(size_t)(g2 * 25 + r) * DD + col];
    partial2[idx] = s;
}

__global__ __launch_bounds__(256) void pool2_kernel(
    const float* __restrict__ partial2, void* __restrict__ out,
    const int* __restrict__ flag) {
    int dd = blockIdx.x * 256 + threadIdx.x;
    if (dd >= DD) return;
    float s = 0.f;
#pragma unroll
    for (int g2 = 0; g2 < 16; g2++) s += partial2[g2 * DD + dd];
    s *= (1.0f / 10000.0f);
    if (*flag) ((__hip_bfloat16*)out)[dd] = __float2bfloat16(s);
    else ((float*)out)[dd] = s;
}

// ---------------- launch ----------------

extern "C" void kernel_launch(void* const* d_in, const int* in_sizes, int n_in,
                              void* d_out, int out_size, void* d_ws, size_t ws_size,
                              hipStream_t stream) {
    const void* x         = d_in[0];
    const void* edge_attr = d_in[1];
    const int*  ei        = (const int*)d_in[2];
    const void* rel_emb   = d_in[3];
    const void* W_edge    = d_in[4];
    const void* b_edge    = d_in[5];
    const void* Wk        = d_in[6];
    const void* bk        = d_in[7];
    const void* Wq        = d_in[8];
    const void* bq        = d_in[9];
    const void* Wv        = d_in[10];
    const void* bv        = d_in[11];
    const void* We        = d_in[12];
    const void* Wskip     = d_in[13];
    const void* bskip     = d_in[14];
    const void* ln_g      = d_in[15];
    const void* ln_b      = d_in[16];

    char* ws = (char*)d_ws;
    // ---- workspace layout (~102.8 MB total) ----
    int*   flag    = (int*)(ws + 0);
    int*   counts  = (int*)(ws + 256);          // 40,000
    int*   rowptr  = (int*)(ws + 40448);        // 40,004
    int*   cursor  = (int*)(ws + 80640);        // 40,000
    int*   eids    = (int*)(ws + 120832);       // 400,000
    int*   esrc    = (int*)(ws + 520960);       // 400,000
    float* ef      = (float*)(ws + 920960);     // 6,400,000
    float* Qe      = (float*)(ws + 7320960);    // 2,560,000
    float* partial = (float*)(ws + 9880960);    // 1,228,800
    float* partial2= (float*)(ws + 11109760);   // 49,152
    __hip_bfloat16* eab   = (__hip_bfloat16*)(ws + 11158912);  // 400,000
    __hip_bfloat16* relb  = (__hip_bfloat16*)(ws + 11559296);  // 300
    __hip_bfloat16* Wedb  = (__hip_bfloat16*)(ws + 11559680);  // 512
    __hip_bfloat16* bedb  = (__hip_bfloat16*)(ws + 11560192);  // 32
    __hip_bfloat16* ballb = (__hip_bfloat16*)(ws + 11560320);  // 18,432
    __hip_bfloat16* lngb  = (__hip_bfloat16*)(ws + 11578752);  // 1,536
    __hip_bfloat16* lnbb  = (__hip_bfloat16*)(ws + 11580288);  // 1,536
    __hip_bfloat16* Web   = (__hip_bfloat16*)(ws + 11581824);  // 73,728
    __hip_bfloat16* hb    = (__hip_bfloat16*)(ws + 11655552);  // 15,532,032 (MP*768)
    __hip_bfloat16* Wt3   = (__hip_bfloat16*)(ws + 27187584);  // 14,155,776
    __hip_bfloat16* qkvs  = (__hip_bfloat16*)(ws + 41343360);  // 61,440,000 -> 102,783,360

    dim3 blk(256);

    detect_kernel<<<dim3(1), dim3(64), 0, stream>>>(edge_attr, flag);

    {
        long long tot = (long long)NN * DD + 3LL * EDIM * DD + (long long)(MP - NN) * DD;
        cvt_big<<<dim3((unsigned)((tot + 255) / 256)), blk, 0, stream>>>(x, We, flag, hb, Web);
    }
    {
        long long tot = 2LL * EE + NREL * (EDIM - 1) + EDIM * EDIM + EDIM
                        + 3LL * NQKV + 2LL * DD;
        cvt_small<<<dim3((unsigned)((tot + 255) / 256)), blk, 0, stream>>>(
            edge_attr, rel_emb, W_edge, b_edge, bk, bq, bv, bskip, ln_g, ln_b,
            flag, eab, relb, Wedb, bedb, ballb, lngb, lnbb);
    }
    wt_all<<<dim3(576, 12), blk, 0, stream>>>(Wq, Wk, Wv, Wskip, flag, Wt3);

    // CSR build
    zero_counts<<<dim3(40), blk, 0, stream>>>(counts);
    count_kernel<<<dim3((EE + 255) / 256), blk, 0, stream>>>(ei, counts);
    scan_kernel<<<dim3(1), blk, 0, stream>>>(counts, rowptr);
    cursor_kernel<<<dim3(40), blk, 0, stream>>>(rowptr, cursor);
    fill_kernel<<<dim3((EE + 255) / 256), blk, 0, stream>>>(ei, cursor, eids, esrc);

    ef_kernel<<<dim3((EE * EDIM) / 256), blk, 0, stream>>>(eab, relb, Wedb, bedb, ef);

    for (int l = 0; l < 3; l++) {
        const __hip_bfloat16* We_l = Web + (size_t)l * EDIM * DD;
        gemm_fused<<<dim3(NQKV / 128, MP / 128), blk, 0, stream>>>(
            hb, Wt3 + (size_t)l * NQKV * DD, ballb + (size_t)l * NQKV, qkvs);
        qe_kernel<<<dim3((NN * 64) / 256), blk, 0, stream>>>(qkvs, We_l, Qe);
        node_attn<<<dim3(NN / 4), blk, 0, stream>>>(rowptr, eids, esrc, qkvs, Qe, ef,
                                                    We_l, hb, (l < 2) ? 1 : 0);
    }

    ln_pool<<<dim3(400), blk, 0, stream>>>(hb, lngb, lnbb, partial);
    pool1_kernel<<<dim3(48), blk, 0, stream>>>(partial, partial2);
    pool2_kernel<<<dim3(3), blk, 0, stream>>>(partial2, d_out, flag);
}